// Round 2
// baseline (503.496 us; speedup 1.0000x reference)
//
#include <hip/hip_runtime.h>
#include <hip/hip_bf16.h>

// ReBASED attention R5: Q-in-registers + fused per-slice QK^T->square->PV.
// The x32-MFMA C-layout of S^T (A=K, B=Q) IS the A-layout of x16 PV MFMA, so
// each 16-row k-slice's P fragment is consumed immediately -> stt/pk live
// range collapses from 48 regs to ~12 -> fits 128-reg cap at 4 blocks/CU
// (R4 spilled: 662MB scratch writes). LDS = K/V double buffers only (37.9KB).
// grid=(64,8): linear id % 8 == head % 8 -> one head's 8 blocks share an XCD L2.

#define SEQ 2048
#define HD  64
#define BQ  128
#define BK  64
#define LQ  72   // Ks stride in shorts (144B rows, b128-aligned cols)
#define LV  76   // Vst stride in shorts (152B rows, b64-aligned, spreads banks)

typedef __attribute__((ext_vector_type(8))) short bf16x8;
typedef __attribute__((ext_vector_type(4))) short bf16x4;
typedef __attribute__((ext_vector_type(4))) float f32x4;

__device__ inline unsigned packbf(float a, float b) {
    __hip_bfloat162 h = __float22bfloat162_rn(make_float2(a, b));  // a->low, b->high
    union { __hip_bfloat162 h2; unsigned u; } cv; cv.h2 = h; return cv.u;
}

__global__ __launch_bounds__(256, 4)
void rebased_r5_kernel(const float* __restrict__ qg,
                       const float* __restrict__ kg,
                       const float* __restrict__ vg,
                       float* __restrict__ og) {
    __shared__ __align__(16) unsigned short Ks[2][BK][LQ];
    __shared__ __align__(16) unsigned short Vst[2][HD][LV];

    const int t    = threadIdx.x;
    const int lane = t & 63;
    const int w    = t >> 6;        // wave: q-rows [w*32, w*32+32)
    const int li   = lane & 15;
    const int qd   = lane >> 4;     // quad
    const int head = blockIdx.x;    // id%8 == head%8 -> head pinned to one XCD
    const int pj   = blockIdx.y;    // 0..7 -> q-tile pair (15-pj, pj)
    const size_t base = (size_t)head * SEQ * HD;

    #pragma unroll
    for (int seg = 0; seg < 2; ++seg) {
        const int qt = seg ? pj : (15 - pj);
        const int ktmax = 2 * qt + 1;

        // ---- Q fragments straight to registers (per-wave private; scaled) ----
        bf16x8 qf[2][2];   // [ks][mt]
        {
            const int qrow0 = qt * BQ + w * 32;
            #pragma unroll
            for (int mt = 0; mt < 2; ++mt) {
                const float* qrow = qg + base + (size_t)(qrow0 + mt * 16 + li) * HD;
                #pragma unroll
                for (int ks = 0; ks < 2; ++ks) {
                    float4 a = *(const float4*)(qrow + ks * 32 + qd * 8);
                    float4 b = *(const float4*)(qrow + ks * 32 + qd * 8 + 4);
                    union { unsigned u[4]; bf16x8 v; } cv;
                    cv.u[0] = packbf(a.x * 0.125f, a.y * 0.125f);
                    cv.u[1] = packbf(a.z * 0.125f, a.w * 0.125f);
                    cv.u[2] = packbf(b.x * 0.125f, b.y * 0.125f);
                    cv.u[3] = packbf(b.z * 0.125f, b.w * 0.125f);
                    qf[ks][mt] = cv.v;
                }
            }
        }

        // ---- load kt=0 K/V into registers ----
        float4 kreg[4], vreg[4];
        {
            const float4* ksrc = (const float4*)(kg + base);
            const float4* vsrc = (const float4*)(vg + base);
            #pragma unroll
            for (int l = 0; l < 4; ++l) kreg[l] = ksrc[t + l * 256];
            const int d4g = t & 15, rp = t >> 4;
            #pragma unroll
            for (int p = 0; p < 2; ++p) {
                int r0 = p * 32 + rp * 2;
                vreg[2 * p]     = vsrc[r0 * 16 + d4g];
                vreg[2 * p + 1] = vsrc[(r0 + 1) * 16 + d4g];
            }
        }
        __syncthreads();   // prior segment's LDS reads complete

        // ---- write kt=0 K/V to LDS ----
        #pragma unroll
        for (int l = 0; l < 4; ++l) {
            int row = (t >> 4) + l * 16, d4 = (t & 15) << 2;
            unsigned* dst = (unsigned*)&Ks[0][row][d4];
            dst[0] = packbf(kreg[l].x, kreg[l].y);
            dst[1] = packbf(kreg[l].z, kreg[l].w);
        }
        {
            const int d4g = t & 15, rp = t >> 4;
            #pragma unroll
            for (int p = 0; p < 2; ++p) {
                int r0 = p * 32 + rp * 2;
                float a0[4] = {vreg[2*p].x, vreg[2*p].y, vreg[2*p].z, vreg[2*p].w};
                float a1[4] = {vreg[2*p+1].x, vreg[2*p+1].y, vreg[2*p+1].z, vreg[2*p+1].w};
                #pragma unroll
                for (int j = 0; j < 4; ++j)
                    *(unsigned*)&Vst[0][d4g * 4 + j][r0] = packbf(a0[j], a1[j]);
            }
        }
        __syncthreads();

        f32x4 oacc[2][4];
        float zpart[2] = {0.f, 0.f};
        #pragma unroll
        for (int mt = 0; mt < 2; ++mt)
            #pragma unroll
            for (int nd = 0; nd < 4; ++nd) oacc[mt][nd] = (f32x4){0.f, 0.f, 0.f, 0.f};

        for (int kt = 0; kt <= ktmax; ++kt) {
            const int cur = kt & 1;

            // ---- prefetch kt+1 K/V into registers (latency hides under compute) ----
            if (kt < ktmax) {
                const float4* ksrc = (const float4*)(kg + base + (size_t)(kt + 1) * BK * HD);
                const float4* vsrc = (const float4*)(vg + base + (size_t)(kt + 1) * BK * HD);
                #pragma unroll
                for (int l = 0; l < 4; ++l) kreg[l] = ksrc[t + l * 256];
                const int d4g = t & 15, rp = t >> 4;
                #pragma unroll
                for (int p = 0; p < 2; ++p) {
                    int r0 = p * 32 + rp * 2;
                    vreg[2 * p]     = vsrc[r0 * 16 + d4g];
                    vreg[2 * p + 1] = vsrc[(r0 + 1) * 16 + d4g];
                }
            }

            const int qrow_min = qt * BQ + w * 32;
            const bool active   = (kt * BK <= qrow_min + 31);
            const bool needmask = (kt * BK + 63 > qrow_min);

            if (active) {
                // ---- fused per 16-row k-slice: S^T mfma -> square/mask -> PV mfma.
                // C-layout of S^T (x32, A=K B=Q) == A-layout of x16 PV MFMA, so
                // each slice's P is consumed immediately; only one slice live.
                #pragma unroll
                for (int nk = 0; nk < 4; ++nk) {
                    f32x4 stt[2];
                    stt[0] = (f32x4){0.f,0.f,0.f,0.f};
                    stt[1] = (f32x4){0.f,0.f,0.f,0.f};
                    #pragma unroll
                    for (int ks = 0; ks < 2; ++ks) {
                        bf16x8 kf = *(const bf16x8*)&Ks[cur][nk * 16 + li][ks * 32 + qd * 8];
                        #pragma unroll
                        for (int mt = 0; mt < 2; ++mt)
                            stt[mt] = __builtin_amdgcn_mfma_f32_16x16x32_bf16(
                                kf, qf[ks][mt], stt[mt], 0, 0, 0);
                    }

                    // square + causal mask + pack to bf16 A-fragment
                    bf16x4 av[2];
                    const int kcb = kt * BK + nk * 16 + qd * 4;
                    #pragma unroll
                    for (int mt = 0; mt < 2; ++mt) {
                        const int qrow = qrow_min + mt * 16 + li;
                        float p[4];
                        #pragma unroll
                        for (int r = 0; r < 4; ++r) {
                            float s = stt[mt][r];
                            if (needmask && (kcb + r > qrow)) s = 0.f;
                            p[r] = s * s;
                        }
                        zpart[mt] += (p[0] + p[1]) + (p[2] + p[3]);
                        union { unsigned u[2]; bf16x4 v; } cv;
                        cv.u[0] = packbf(p[0], p[1]);
                        cv.u[1] = packbf(p[2], p[3]);
                        av[mt] = cv.v;
                    }

                    // O += P-slice * V-slice (x16 MFMA, B=V^T from LDS)
                    #pragma unroll
                    for (int nd = 0; nd < 4; ++nd) {
                        bf16x4 vf = *(const bf16x4*)&Vst[cur][nd * 16 + li][nk * 16 + qd * 4];
                        #pragma unroll
                        for (int mt = 0; mt < 2; ++mt)
                            oacc[mt][nd] = __builtin_amdgcn_mfma_f32_16x16x16bf16_1k(
                                av[mt], vf, oacc[mt][nd], 0, 0, 0);
                    }
                }
            }

            // ---- write prefetched kt+1 into the other buffer ----
            if (kt < ktmax) {
                const int nb = cur ^ 1;
                #pragma unroll
                for (int l = 0; l < 4; ++l) {
                    int row = (t >> 4) + l * 16, d4 = (t & 15) << 2;
                    unsigned* dst = (unsigned*)&Ks[nb][row][d4];
                    dst[0] = packbf(kreg[l].x, kreg[l].y);
                    dst[1] = packbf(kreg[l].z, kreg[l].w);
                }
                const int d4g = t & 15, rp = t >> 4;
                #pragma unroll
                for (int p = 0; p < 2; ++p) {
                    int r0 = p * 32 + rp * 2;
                    float a0[4] = {vreg[2*p].x, vreg[2*p].y, vreg[2*p].z, vreg[2*p].w};
                    float a1[4] = {vreg[2*p+1].x, vreg[2*p+1].y, vreg[2*p+1].z, vreg[2*p+1].w};
                    #pragma unroll
                    for (int j = 0; j < 4; ++j)
                        *(unsigned*)&Vst[nb][d4g * 4 + j][r0] = packbf(a0[j], a1[j]);
                }
            }
            __syncthreads();
        }

        // ---- epilogue: z reduce (quads) + divide + store ----
        float* odst = og + base + (size_t)qt * BQ * HD;
        #pragma unroll
        for (int mt = 0; mt < 2; ++mt) {
            float zf = zpart[mt];
            zf += __shfl_xor(zf, 16, 64);
            zf += __shfl_xor(zf, 32, 64);   // all lanes: z for qrow = mt*16 + li
            #pragma unroll
            for (int r = 0; r < 4; ++r) {
                float zr = __shfl(zf, qd * 4 + r, 64);
                float inv = 1.f / (zr + 1e-6f);
                int row = w * 32 + mt * 16 + qd * 4 + r;
                #pragma unroll
                for (int nd = 0; nd < 4; ++nd)
                    odst[row * HD + nd * 16 + li] = oacc[mt][nd][r] * inv;
            }
        }
    }
}

extern "C" void kernel_launch(void* const* d_in, const int* in_sizes, int n_in,
                              void* d_out, int out_size, void* d_ws, size_t ws_size,
                              hipStream_t stream) {
    const float* q = (const float*)d_in[0];
    const float* k = (const float*)d_in[1];
    const float* v = (const float*)d_in[2];
    float* out = (float*)d_out;

    dim3 grid(64, 8);    // head-major: all 8 q-tile blocks of a head on one XCD
    dim3 block(256);
    rebased_r5_kernel<<<grid, block, 0, stream>>>(q, k, v, out);
}

// Round 3
// 218.040 us; speedup vs baseline: 2.3092x; 2.3092x over previous
//
#include <hip/hip_runtime.h>
#include <hip/hip_bf16.h>

// ReBASED attention R6: R5 structure with a *fitting* register budget.
// R4/R5 post-mortem: __launch_bounds__(256,4) = 128-reg cap (unified VGPR+AGPR
// on gfx950); kernel's natural footprint ~150 -> massive scratch spill
// (WRITE_SIZE 0.66-1.0 GB, VGPR_Count pinned at 64). Fix: (256,3) -> ~170-reg
// budget, 12 waves/CU (3 blocks/CU; LDS 37.9KB would allow 4 but VGPR binds).
// Still 1.5x R3's occupancy with zero spill.
// Kept from R5: Q fragments in registers (no Q LDS, no per-kt Q re-reads);
// fused per-16-row-slice QK^T -> square -> PV (S^T C-layout == PV A-layout);
// grid=(64,8) so one head's 8 blocks share an XCD L2 for K/V.

#define SEQ 2048
#define HD  64
#define BQ  128
#define BK  64
#define LQ  72   // Ks stride in shorts (144B rows, b128-aligned cols)
#define LV  76   // Vst stride in shorts (152B rows, b64-aligned, spreads banks)

typedef __attribute__((ext_vector_type(8))) short bf16x8;
typedef __attribute__((ext_vector_type(4))) short bf16x4;
typedef __attribute__((ext_vector_type(4))) float f32x4;

__device__ inline unsigned packbf(float a, float b) {
    __hip_bfloat162 h = __float22bfloat162_rn(make_float2(a, b));  // a->low, b->high
    union { __hip_bfloat162 h2; unsigned u; } cv; cv.h2 = h; return cv.u;
}

__global__ __launch_bounds__(256, 3)
void rebased_r6_kernel(const float* __restrict__ qg,
                       const float* __restrict__ kg,
                       const float* __restrict__ vg,
                       float* __restrict__ og) {
    __shared__ __align__(16) unsigned short Ks[2][BK][LQ];
    __shared__ __align__(16) unsigned short Vst[2][HD][LV];

    const int t    = threadIdx.x;
    const int lane = t & 63;
    const int w    = t >> 6;        // wave: q-rows [w*32, w*32+32)
    const int li   = lane & 15;
    const int qd   = lane >> 4;     // quad
    const int head = blockIdx.x;    // id%8 == head%8 -> head pinned to one XCD
    const int pj   = blockIdx.y;    // 0..7 -> q-tile pair (15-pj, pj)
    const size_t base = (size_t)head * SEQ * HD;

    #pragma unroll
    for (int seg = 0; seg < 2; ++seg) {
        const int qt = seg ? pj : (15 - pj);
        const int ktmax = 2 * qt + 1;

        // ---- Q fragments straight to registers (per-wave private; scaled) ----
        bf16x8 qf[2][2];   // [ks][mt]
        {
            const int qrow0 = qt * BQ + w * 32;
            #pragma unroll
            for (int mt = 0; mt < 2; ++mt) {
                const float* qrow = qg + base + (size_t)(qrow0 + mt * 16 + li) * HD;
                #pragma unroll
                for (int ks = 0; ks < 2; ++ks) {
                    float4 a = *(const float4*)(qrow + ks * 32 + qd * 8);
                    float4 b = *(const float4*)(qrow + ks * 32 + qd * 8 + 4);
                    union { unsigned u[4]; bf16x8 v; } cv;
                    cv.u[0] = packbf(a.x * 0.125f, a.y * 0.125f);
                    cv.u[1] = packbf(a.z * 0.125f, a.w * 0.125f);
                    cv.u[2] = packbf(b.x * 0.125f, b.y * 0.125f);
                    cv.u[3] = packbf(b.z * 0.125f, b.w * 0.125f);
                    qf[ks][mt] = cv.v;
                }
            }
        }

        // ---- load kt=0 K/V into registers ----
        float4 kreg[4], vreg[4];
        {
            const float4* ksrc = (const float4*)(kg + base);
            const float4* vsrc = (const float4*)(vg + base);
            #pragma unroll
            for (int l = 0; l < 4; ++l) kreg[l] = ksrc[t + l * 256];
            const int d4g = t & 15, rp = t >> 4;
            #pragma unroll
            for (int p = 0; p < 2; ++p) {
                int r0 = p * 32 + rp * 2;
                vreg[2 * p]     = vsrc[r0 * 16 + d4g];
                vreg[2 * p + 1] = vsrc[(r0 + 1) * 16 + d4g];
            }
        }
        __syncthreads();   // prior segment's LDS reads complete

        // ---- write kt=0 K/V to LDS ----
        #pragma unroll
        for (int l = 0; l < 4; ++l) {
            int row = (t >> 4) + l * 16, d4 = (t & 15) << 2;
            unsigned* dst = (unsigned*)&Ks[0][row][d4];
            dst[0] = packbf(kreg[l].x, kreg[l].y);
            dst[1] = packbf(kreg[l].z, kreg[l].w);
        }
        {
            const int d4g = t & 15, rp = t >> 4;
            #pragma unroll
            for (int p = 0; p < 2; ++p) {
                int r0 = p * 32 + rp * 2;
                float a0[4] = {vreg[2*p].x, vreg[2*p].y, vreg[2*p].z, vreg[2*p].w};
                float a1[4] = {vreg[2*p+1].x, vreg[2*p+1].y, vreg[2*p+1].z, vreg[2*p+1].w};
                #pragma unroll
                for (int j = 0; j < 4; ++j)
                    *(unsigned*)&Vst[0][d4g * 4 + j][r0] = packbf(a0[j], a1[j]);
            }
        }
        __syncthreads();

        f32x4 oacc[2][4];
        float zpart[2] = {0.f, 0.f};
        #pragma unroll
        for (int mt = 0; mt < 2; ++mt)
            #pragma unroll
            for (int nd = 0; nd < 4; ++nd) oacc[mt][nd] = (f32x4){0.f, 0.f, 0.f, 0.f};

        for (int kt = 0; kt <= ktmax; ++kt) {
            const int cur = kt & 1;

            // ---- prefetch kt+1 K/V into registers (latency hides under compute) ----
            if (kt < ktmax) {
                const float4* ksrc = (const float4*)(kg + base + (size_t)(kt + 1) * BK * HD);
                const float4* vsrc = (const float4*)(vg + base + (size_t)(kt + 1) * BK * HD);
                #pragma unroll
                for (int l = 0; l < 4; ++l) kreg[l] = ksrc[t + l * 256];
                const int d4g = t & 15, rp = t >> 4;
                #pragma unroll
                for (int p = 0; p < 2; ++p) {
                    int r0 = p * 32 + rp * 2;
                    vreg[2 * p]     = vsrc[r0 * 16 + d4g];
                    vreg[2 * p + 1] = vsrc[(r0 + 1) * 16 + d4g];
                }
            }

            const int qrow_min = qt * BQ + w * 32;
            const bool active   = (kt * BK <= qrow_min + 31);
            const bool needmask = (kt * BK + 63 > qrow_min);

            if (active) {
                // ---- fused per 16-row k-slice: S^T mfma -> square/mask -> PV mfma.
                // C-layout of S^T (x32, A=K B=Q) == A-layout of x16 PV MFMA, so
                // each slice's P is consumed immediately; only one slice live.
                #pragma unroll
                for (int nk = 0; nk < 4; ++nk) {
                    f32x4 stt[2];
                    stt[0] = (f32x4){0.f,0.f,0.f,0.f};
                    stt[1] = (f32x4){0.f,0.f,0.f,0.f};
                    #pragma unroll
                    for (int ks = 0; ks < 2; ++ks) {
                        bf16x8 kf = *(const bf16x8*)&Ks[cur][nk * 16 + li][ks * 32 + qd * 8];
                        #pragma unroll
                        for (int mt = 0; mt < 2; ++mt)
                            stt[mt] = __builtin_amdgcn_mfma_f32_16x16x32_bf16(
                                kf, qf[ks][mt], stt[mt], 0, 0, 0);
                    }

                    // square + causal mask + pack to bf16 A-fragment
                    bf16x4 av[2];
                    const int kcb = kt * BK + nk * 16 + qd * 4;
                    #pragma unroll
                    for (int mt = 0; mt < 2; ++mt) {
                        const int qrow = qrow_min + mt * 16 + li;
                        float p[4];
                        #pragma unroll
                        for (int r = 0; r < 4; ++r) {
                            float s = stt[mt][r];
                            if (needmask && (kcb + r > qrow)) s = 0.f;
                            p[r] = s * s;
                        }
                        zpart[mt] += (p[0] + p[1]) + (p[2] + p[3]);
                        union { unsigned u[2]; bf16x4 v; } cv;
                        cv.u[0] = packbf(p[0], p[1]);
                        cv.u[1] = packbf(p[2], p[3]);
                        av[mt] = cv.v;
                    }

                    // O += P-slice * V-slice (x16 MFMA, B=V^T from LDS)
                    #pragma unroll
                    for (int nd = 0; nd < 4; ++nd) {
                        bf16x4 vf = *(const bf16x4*)&Vst[cur][nd * 16 + li][nk * 16 + qd * 4];
                        #pragma unroll
                        for (int mt = 0; mt < 2; ++mt)
                            oacc[mt][nd] = __builtin_amdgcn_mfma_f32_16x16x16bf16_1k(
                                av[mt], vf, oacc[mt][nd], 0, 0, 0);
                    }
                }
            }

            // ---- write prefetched kt+1 into the other buffer ----
            if (kt < ktmax) {
                const int nb = cur ^ 1;
                #pragma unroll
                for (int l = 0; l < 4; ++l) {
                    int row = (t >> 4) + l * 16, d4 = (t & 15) << 2;
                    unsigned* dst = (unsigned*)&Ks[nb][row][d4];
                    dst[0] = packbf(kreg[l].x, kreg[l].y);
                    dst[1] = packbf(kreg[l].z, kreg[l].w);
                }
                const int d4g = t & 15, rp = t >> 4;
                #pragma unroll
                for (int p = 0; p < 2; ++p) {
                    int r0 = p * 32 + rp * 2;
                    float a0[4] = {vreg[2*p].x, vreg[2*p].y, vreg[2*p].z, vreg[2*p].w};
                    float a1[4] = {vreg[2*p+1].x, vreg[2*p+1].y, vreg[2*p+1].z, vreg[2*p+1].w};
                    #pragma unroll
                    for (int j = 0; j < 4; ++j)
                        *(unsigned*)&Vst[nb][d4g * 4 + j][r0] = packbf(a0[j], a1[j]);
                }
            }
            __syncthreads();
        }

        // ---- epilogue: z reduce (quads) + divide + store ----
        float* odst = og + base + (size_t)qt * BQ * HD;
        #pragma unroll
        for (int mt = 0; mt < 2; ++mt) {
            float zf = zpart[mt];
            zf += __shfl_xor(zf, 16, 64);
            zf += __shfl_xor(zf, 32, 64);   // all lanes: z for qrow = mt*16 + li
            #pragma unroll
            for (int r = 0; r < 4; ++r) {
                float zr = __shfl(zf, qd * 4 + r, 64);
                float inv = 1.f / (zr + 1e-6f);
                int row = w * 32 + mt * 16 + qd * 4 + r;
                #pragma unroll
                for (int nd = 0; nd < 4; ++nd)
                    odst[row * HD + nd * 16 + li] = oacc[mt][nd][r] * inv;
            }
        }
    }
}

extern "C" void kernel_launch(void* const* d_in, const int* in_sizes, int n_in,
                              void* d_out, int out_size, void* d_ws, size_t ws_size,
                              hipStream_t stream) {
    const float* q = (const float*)d_in[0];
    const float* k = (const float*)d_in[1];
    const float* v = (const float*)d_in[2];
    float* out = (float*)d_out;

    dim3 grid(64, 8);    // head-major: all 8 q-tile blocks of a head on one XCD
    dim3 block(256);
    rebased_r6_kernel<<<grid, block, 0, stream>>>(q, k, v, out);
}

// Round 4
// 200.204 us; speedup vs baseline: 2.5149x; 1.0891x over previous
//
#include <hip/hip_runtime.h>
#include <hip/hip_bf16.h>

// ReBASED attention R7: one q-tile per block, heavy-first dispatch, 3 blocks/CU.
// R6 post-mortem: grid=512 capped residency at 2 blocks/CU (the (256,3) budget
// was irrelevant), and per-slice fusion serialized QK->VALU->PV (13us slower
// than R3's separated phases at equal occupancy).
// Fixes: grid=(64,16)=1024 blocks, qt = 15 - blockIdx.y so heaviest (32-iter)
// blocks dispatch first and 2-iter blocks fill the tail (LPT balancing);
// phase-separated k-body (8 indep QK MFMAs -> VALU block -> 32 PV MFMAs) fits
// the (256,3) ~170-reg budget (R4 only spilled under the 128-reg (256,4) cap).
// Kept: Q fragments in registers (no Q LDS), S^T orientation (QK C-layout ==
// PV A-layout, no P roundtrip), K/V double-buffer reg-prefetch,
// grid.x = head -> id%8 == head%8 pins each head's blocks to one XCD L2
// (R6 proved FETCH drops to compulsory 100MB).

#define SEQ 2048
#define HD  64
#define BQ  128
#define BK  64
#define LQ  72   // Ks stride in shorts (144B rows, b128-aligned cols)
#define LV  76   // Vst stride in shorts (152B rows, b64-aligned, spreads banks)

typedef __attribute__((ext_vector_type(8))) short bf16x8;
typedef __attribute__((ext_vector_type(4))) short bf16x4;
typedef __attribute__((ext_vector_type(4))) float f32x4;

__device__ inline unsigned packbf(float a, float b) {
    __hip_bfloat162 h = __float22bfloat162_rn(make_float2(a, b));  // a->low, b->high
    union { __hip_bfloat162 h2; unsigned u; } cv; cv.h2 = h; return cv.u;
}

__global__ __launch_bounds__(256, 3)
void rebased_r7_kernel(const float* __restrict__ qg,
                       const float* __restrict__ kg,
                       const float* __restrict__ vg,
                       float* __restrict__ og) {
    __shared__ __align__(16) unsigned short Ks[2][BK][LQ];
    __shared__ __align__(16) unsigned short Vst[2][HD][LV];

    const int t    = threadIdx.x;
    const int lane = t & 63;
    const int w    = t >> 6;        // wave: q-rows [w*32, w*32+32)
    const int li   = lane & 15;
    const int qd   = lane >> 4;     // quad
    const int head = blockIdx.x;    // id%8 == head%8 -> head pinned to one XCD
    const int qt   = 15 - blockIdx.y;  // heavy-first: qt=15 (32 iters) dispatches first
    const int ktmax = 2 * qt + 1;
    const size_t base = (size_t)head * SEQ * HD;

    // ---- Q fragments straight to registers (per-wave private; scaled) ----
    bf16x8 qf[2][2];   // [ks][mt]
    {
        const int qrow0 = qt * BQ + w * 32;
        #pragma unroll
        for (int mt = 0; mt < 2; ++mt) {
            const float* qrow = qg + base + (size_t)(qrow0 + mt * 16 + li) * HD;
            #pragma unroll
            for (int ks = 0; ks < 2; ++ks) {
                float4 a = *(const float4*)(qrow + ks * 32 + qd * 8);
                float4 b = *(const float4*)(qrow + ks * 32 + qd * 8 + 4);
                union { unsigned u[4]; bf16x8 v; } cv;
                cv.u[0] = packbf(a.x * 0.125f, a.y * 0.125f);
                cv.u[1] = packbf(a.z * 0.125f, a.w * 0.125f);
                cv.u[2] = packbf(b.x * 0.125f, b.y * 0.125f);
                cv.u[3] = packbf(b.z * 0.125f, b.w * 0.125f);
                qf[ks][mt] = cv.v;
            }
        }
    }

    // ---- load kt=0 K/V into registers, write to LDS buffer 0 ----
    float4 kreg[4], vreg[4];
    {
        const float4* ksrc = (const float4*)(kg + base);
        const float4* vsrc = (const float4*)(vg + base);
        #pragma unroll
        for (int l = 0; l < 4; ++l) kreg[l] = ksrc[t + l * 256];
        const int d4g = t & 15, rp = t >> 4;
        #pragma unroll
        for (int p = 0; p < 2; ++p) {
            int r0 = p * 32 + rp * 2;
            vreg[2 * p]     = vsrc[r0 * 16 + d4g];
            vreg[2 * p + 1] = vsrc[(r0 + 1) * 16 + d4g];
        }
    }
    #pragma unroll
    for (int l = 0; l < 4; ++l) {
        int row = (t >> 4) + l * 16, d4 = (t & 15) << 2;
        unsigned* dst = (unsigned*)&Ks[0][row][d4];
        dst[0] = packbf(kreg[l].x, kreg[l].y);
        dst[1] = packbf(kreg[l].z, kreg[l].w);
    }
    {
        const int d4g = t & 15, rp = t >> 4;
        #pragma unroll
        for (int p = 0; p < 2; ++p) {
            int r0 = p * 32 + rp * 2;
            float a0[4] = {vreg[2*p].x, vreg[2*p].y, vreg[2*p].z, vreg[2*p].w};
            float a1[4] = {vreg[2*p+1].x, vreg[2*p+1].y, vreg[2*p+1].z, vreg[2*p+1].w};
            #pragma unroll
            for (int j = 0; j < 4; ++j)
                *(unsigned*)&Vst[0][d4g * 4 + j][r0] = packbf(a0[j], a1[j]);
        }
    }
    __syncthreads();

    f32x4 oacc[2][4];
    float zpart[2] = {0.f, 0.f};
    #pragma unroll
    for (int mt = 0; mt < 2; ++mt)
        #pragma unroll
        for (int nd = 0; nd < 4; ++nd) oacc[mt][nd] = (f32x4){0.f, 0.f, 0.f, 0.f};

    for (int kt = 0; kt <= ktmax; ++kt) {
        const int cur = kt & 1;

        // ---- prefetch kt+1 K/V into registers (latency hides under compute) ----
        if (kt < ktmax) {
            const float4* ksrc = (const float4*)(kg + base + (size_t)(kt + 1) * BK * HD);
            const float4* vsrc = (const float4*)(vg + base + (size_t)(kt + 1) * BK * HD);
            #pragma unroll
            for (int l = 0; l < 4; ++l) kreg[l] = ksrc[t + l * 256];
            const int d4g = t & 15, rp = t >> 4;
            #pragma unroll
            for (int p = 0; p < 2; ++p) {
                int r0 = p * 32 + rp * 2;
                vreg[2 * p]     = vsrc[r0 * 16 + d4g];
                vreg[2 * p + 1] = vsrc[(r0 + 1) * 16 + d4g];
            }
        }

        const int qrow_min = qt * BQ + w * 32;
        const bool active   = (kt * BK <= qrow_min + 31);
        const bool needmask = (kt * BK + 63 > qrow_min);

        if (active) {
            // ---- S^T = K·Q^T : x32 MFMA, A=K-frag (LDS), B=Q-frag (regs) ----
            f32x4 stt[4][2];
            #pragma unroll
            for (int nk = 0; nk < 4; ++nk)
                #pragma unroll
                for (int mt = 0; mt < 2; ++mt) stt[nk][mt] = (f32x4){0.f,0.f,0.f,0.f};
            #pragma unroll
            for (int ks = 0; ks < 2; ++ks) {
                const int kb = ks * 32 + qd * 8;
                bf16x8 kf[4];
                #pragma unroll
                for (int nk = 0; nk < 4; ++nk)
                    kf[nk] = *(const bf16x8*)&Ks[cur][nk * 16 + li][kb];
                #pragma unroll
                for (int nk = 0; nk < 4; ++nk)
                    #pragma unroll
                    for (int mt = 0; mt < 2; ++mt)
                        stt[nk][mt] = __builtin_amdgcn_mfma_f32_16x16x32_bf16(
                            kf[nk], qf[ks][mt], stt[nk][mt], 0, 0, 0);
            }

            // ---- square + mask + pack: C-layout of S^T == A-layout for x16 MFMA ----
            unsigned pk[4][2][2];
            #pragma unroll
            for (int nk = 0; nk < 4; ++nk) {
                const int kcb = kt * BK + nk * 16 + qd * 4;
                #pragma unroll
                for (int mt = 0; mt < 2; ++mt) {
                    const int qrow = qrow_min + mt * 16 + li;
                    float p[4];
                    #pragma unroll
                    for (int r = 0; r < 4; ++r) {
                        float s = stt[nk][mt][r];
                        if (needmask && (kcb + r > qrow)) s = 0.f;
                        p[r] = s * s;
                    }
                    zpart[mt] += (p[0] + p[1]) + (p[2] + p[3]);
                    pk[nk][mt][0] = packbf(p[0], p[1]);
                    pk[nk][mt][1] = packbf(p[2], p[3]);
                }
            }

            // ---- O += P·V : x16 MFMA, A=P (in regs), B=V^T from LDS ----
            #pragma unroll
            for (int ks16 = 0; ks16 < 4; ++ks16) {
                bf16x4 av[2];
                #pragma unroll
                for (int mt = 0; mt < 2; ++mt) {
                    union { unsigned u[2]; bf16x4 v; } cv;
                    cv.u[0] = pk[ks16][mt][0]; cv.u[1] = pk[ks16][mt][1];
                    av[mt] = cv.v;
                }
                #pragma unroll
                for (int nd = 0; nd < 4; ++nd) {
                    bf16x4 vf = *(const bf16x4*)&Vst[cur][nd * 16 + li][ks16 * 16 + qd * 4];
                    #pragma unroll
                    for (int mt = 0; mt < 2; ++mt)
                        oacc[mt][nd] = __builtin_amdgcn_mfma_f32_16x16x16bf16_1k(
                            av[mt], vf, oacc[mt][nd], 0, 0, 0);
                }
            }
        }

        // ---- write prefetched kt+1 into the other buffer ----
        if (kt < ktmax) {
            const int nb = cur ^ 1;
            #pragma unroll
            for (int l = 0; l < 4; ++l) {
                int row = (t >> 4) + l * 16, d4 = (t & 15) << 2;
                unsigned* dst = (unsigned*)&Ks[nb][row][d4];
                dst[0] = packbf(kreg[l].x, kreg[l].y);
                dst[1] = packbf(kreg[l].z, kreg[l].w);
            }
            const int d4g = t & 15, rp = t >> 4;
            #pragma unroll
            for (int p = 0; p < 2; ++p) {
                int r0 = p * 32 + rp * 2;
                float a0[4] = {vreg[2*p].x, vreg[2*p].y, vreg[2*p].z, vreg[2*p].w};
                float a1[4] = {vreg[2*p+1].x, vreg[2*p+1].y, vreg[2*p+1].z, vreg[2*p+1].w};
                #pragma unroll
                for (int j = 0; j < 4; ++j)
                    *(unsigned*)&Vst[nb][d4g * 4 + j][r0] = packbf(a0[j], a1[j]);
            }
        }
        __syncthreads();
    }

    // ---- epilogue: z reduce (quads) + divide + store ----
    float* odst = og + base + (size_t)qt * BQ * HD;
    #pragma unroll
    for (int mt = 0; mt < 2; ++mt) {
        float zf = zpart[mt];
        zf += __shfl_xor(zf, 16, 64);
        zf += __shfl_xor(zf, 32, 64);   // all lanes: z for qrow = mt*16 + li
        #pragma unroll
        for (int r = 0; r < 4; ++r) {
            float zr = __shfl(zf, qd * 4 + r, 64);
            float inv = 1.f / (zr + 1e-6f);
            int row = w * 32 + mt * 16 + qd * 4 + r;
            #pragma unroll
            for (int nd = 0; nd < 4; ++nd)
                odst[row * HD + nd * 16 + li] = oacc[mt][nd][r] * inv;
        }
    }
}

extern "C" void kernel_launch(void* const* d_in, const int* in_sizes, int n_in,
                              void* d_out, int out_size, void* d_ws, size_t ws_size,
                              hipStream_t stream) {
    const float* q = (const float*)d_in[0];
    const float* k = (const float*)d_in[1];
    const float* v = (const float*)d_in[2];
    float* out = (float*)d_out;

    dim3 grid(64, 16);   // x=head (XCD affinity), y: heavy q-tiles first
    dim3 block(256);
    rebased_r7_kernel<<<grid, block, 0, stream>>>(q, k, v, out);
}

// Round 5
// 189.522 us; speedup vs baseline: 2.6567x; 1.0564x over previous
//
#include <hip/hip_runtime.h>
#include <hip/hip_bf16.h>

// ReBASED attention R8: bf16 pre-pass + global_load_lds staging + swizzled LDS.
// R7 post-mortem: latency-bound at 2 blocks/CU; VALU (busiest pipe, 37%) was
// dominated by per-kt f32->bf16 staging (32 regs of float4 = the reason 128-reg
// never fit), redone 16x per head; 5.5M LDS bank-conflict cycles.
// R8: pre-pass converts K -> bf16 and V -> V^T bf16 ONCE into workspace, in
// XOR-swizzled "LDS-image" layout (K: 16B group g^=row&7, V: 8B group sg^=d&15).
// Main kernel stages tiles via __builtin_amdgcn_global_load_lds(16B): no staging
// regs, no conversion VALU, no ds_writes, conflict-free swizzled ds_reads.
// Register footprint ~100 -> __launch_bounds__(256,4) fits (spill source deleted,
// not estimated away). LDS 32KB (no padding: swizzle replaces it).
// Kept: S^T orientation (QK C-layout == PV A-layout), Q-frags in regs,
// heavy-first grid(64,16) with head-per-XCD affinity, double-buffered K/V.

#define SEQ 2048
#define HD  64
#define BQ  128
#define BK  64

typedef __attribute__((ext_vector_type(8))) short bf16x8;
typedef __attribute__((ext_vector_type(4))) short bf16x4;
typedef __attribute__((ext_vector_type(4))) float f32x4;
typedef __attribute__((ext_vector_type(4))) unsigned u32x4;

__device__ inline unsigned packbf(float a, float b) {
    __hip_bfloat162 h = __float22bfloat162_rn(make_float2(a, b));  // a->low, b->high
    union { __hip_bfloat162 h2; unsigned u; } cv; cv.h2 = h; return cv.u;
}

__device__ inline void gload_lds16(const void* g, void* l) {
    __builtin_amdgcn_global_load_lds(
        (const __attribute__((address_space(1))) unsigned*)g,
        (__attribute__((address_space(3))) unsigned*)l, 16, 0, 0);
}

// ---------------- pre-pass: K/V -> bf16 swizzled LDS-image tiles ----------------
// K tile (64x64): kws[tile][r][g'*8..] = K[r][g*8..+7], g' = g ^ (r&7)   (16B groups)
// V tile (64x64): vws[tile][d][sg'*4..] = V[sg*4..+3][d], sg' = sg ^ (d&15) (8B groups)
__global__ __launch_bounds__(256)
void convert_kv_kernel(const float* __restrict__ kg, const float* __restrict__ vg,
                       unsigned short* __restrict__ kws, unsigned short* __restrict__ vws) {
    const int head = blockIdx.x;
    const int kt   = blockIdx.y;
    const int t    = threadIdx.x;
    const size_t gbase = (size_t)head * SEQ * HD + (size_t)kt * BK * HD;
    unsigned short* ktile = kws + gbase;
    unsigned short* vtile = vws + gbase;

    // K: thread t handles row r = t>>2, groups g = (t&3)*2, (t&3)*2+1
    {
        const int r = t >> 2, qr = t & 3;
        #pragma unroll
        for (int gg = 0; gg < 2; ++gg) {
            const int g = qr * 2 + gg;
            float4 a = *(const float4*)(kg + gbase + r * HD + g * 8);
            float4 b = *(const float4*)(kg + gbase + r * HD + g * 8 + 4);
            u32x4 pkd;
            pkd[0] = packbf(a.x, a.y); pkd[1] = packbf(a.z, a.w);
            pkd[2] = packbf(b.x, b.y); pkd[3] = packbf(b.z, b.w);
            *(u32x4*)(ktile + r * 64 + ((g ^ (r & 7)) << 3)) = pkd;
        }
    }
    // V: thread t handles d = t&63, sg = (t>>6) + {0,4,8,12}
    {
        const int d = t & 63, sg0 = t >> 6;
        #pragma unroll
        for (int i = 0; i < 4; ++i) {
            const int sg = sg0 + i * 4;
            float v0 = vg[gbase + (sg * 4 + 0) * HD + d];
            float v1 = vg[gbase + (sg * 4 + 1) * HD + d];
            float v2 = vg[gbase + (sg * 4 + 2) * HD + d];
            float v3 = vg[gbase + (sg * 4 + 3) * HD + d];
            uint2 pkd = make_uint2(packbf(v0, v1), packbf(v2, v3));
            *(uint2*)(vtile + d * 64 + ((sg ^ (d & 15)) << 2)) = pkd;
        }
    }
}

// ---------------- main kernel ----------------
__global__ __launch_bounds__(256, 4)
void rebased_r8_kernel(const float* __restrict__ qg,
                       const unsigned short* __restrict__ kws,
                       const unsigned short* __restrict__ vws,
                       float* __restrict__ og) {
    __shared__ __align__(16) unsigned short Ks[2][BK][HD];    // swizzled image, 8KB each
    __shared__ __align__(16) unsigned short Vst[2][HD][BK];   // swizzled V^T image

    const int t    = threadIdx.x;
    const int lane = t & 63;
    const int w    = t >> 6;        // wave: q-rows [w*32, w*32+32)
    const int li   = lane & 15;
    const int qd   = lane >> 4;     // quad
    const int head = blockIdx.x;    // id%8 == head%8 -> head pinned to one XCD
    const int qt   = 15 - blockIdx.y;  // heavy-first (LPT)
    const int ktmax = 2 * qt + 1;
    const size_t base = (size_t)head * SEQ * HD;

    // ---- Q fragments straight to registers (per-wave private; scaled) ----
    bf16x8 qf[2][2];   // [ks][mt]
    {
        const int qrow0 = qt * BQ + w * 32;
        #pragma unroll
        for (int mt = 0; mt < 2; ++mt) {
            const float* qrow = qg + base + (size_t)(qrow0 + mt * 16 + li) * HD;
            #pragma unroll
            for (int ks = 0; ks < 2; ++ks) {
                float4 a = *(const float4*)(qrow + ks * 32 + qd * 8);
                float4 b = *(const float4*)(qrow + ks * 32 + qd * 8 + 4);
                union { unsigned u[4]; bf16x8 v; } cv;
                cv.u[0] = packbf(a.x * 0.125f, a.y * 0.125f);
                cv.u[1] = packbf(a.z * 0.125f, a.w * 0.125f);
                cv.u[2] = packbf(b.x * 0.125f, b.y * 0.125f);
                cv.u[3] = packbf(b.z * 0.125f, b.w * 0.125f);
                qf[ks][mt] = cv.v;
            }
        }
    }

    // ---- DMA staging: wave w fills bytes [l*4096 + w*1024 + lane*16) of each tile ----
    const int woff = w * 1024;           // wave-uniform LDS byte offset
    const int goff = woff + lane * 16;   // per-lane global byte offset
    #define STAGE(b, kt2)                                                          \
    {                                                                              \
        const char* ksrc = (const char*)(kws + base + (size_t)(kt2) * BK * HD);    \
        const char* vsrc = (const char*)(vws + base + (size_t)(kt2) * BK * HD);    \
        char* kdst = (char*)&Ks[b][0][0];                                          \
        char* vdst = (char*)&Vst[b][0][0];                                         \
        gload_lds16(ksrc + goff,        kdst + woff);                              \
        gload_lds16(ksrc + goff + 4096, kdst + woff + 4096);                       \
        gload_lds16(vsrc + goff,        vdst + woff);                              \
        gload_lds16(vsrc + goff + 4096, vdst + woff + 4096);                       \
    }

    STAGE(0, 0);
    __syncthreads();   // drains vmcnt(0): kt=0 tiles ready

    f32x4 oacc[2][4];
    float zpart[2] = {0.f, 0.f};
    #pragma unroll
    for (int mt = 0; mt < 2; ++mt)
        #pragma unroll
        for (int nd = 0; nd < 4; ++nd) oacc[mt][nd] = (f32x4){0.f, 0.f, 0.f, 0.f};

    for (int kt = 0; kt <= ktmax; ++kt) {
        const int cur = kt & 1;

        // prefetch kt+1 straight into the other LDS buffer (in flight across compute)
        if (kt < ktmax) STAGE(cur ^ 1, kt + 1);

        const int qrow_min = qt * BQ + w * 32;
        const bool active   = (kt * BK <= qrow_min + 31);
        const bool needmask = (kt * BK + 63 > qrow_min);

        if (active) {
            // two independent halves: QK (x32) -> square/mask/pack -> PV (x16)
            #pragma unroll
            for (int h = 0; h < 2; ++h) {
                f32x4 stt[2][2];   // [nk-in-half][mt]
                #pragma unroll
                for (int n2 = 0; n2 < 2; ++n2)
                    #pragma unroll
                    for (int mt = 0; mt < 2; ++mt) stt[n2][mt] = (f32x4){0.f,0.f,0.f,0.f};
                #pragma unroll
                for (int ks = 0; ks < 2; ++ks) {
                    bf16x8 kf[2];
                    #pragma unroll
                    for (int n2 = 0; n2 < 2; ++n2) {
                        const int row = (h * 2 + n2) * 16 + li;
                        const int grp = ((ks * 4 + qd) ^ (li & 7)) << 3;  // swizzled 16B group
                        kf[n2] = *(const bf16x8*)&Ks[cur][row][grp];
                    }
                    #pragma unroll
                    for (int n2 = 0; n2 < 2; ++n2)
                        #pragma unroll
                        for (int mt = 0; mt < 2; ++mt)
                            stt[n2][mt] = __builtin_amdgcn_mfma_f32_16x16x32_bf16(
                                kf[n2], qf[ks][mt], stt[n2][mt], 0, 0, 0);
                }

                // square + causal mask + pack (C-layout of S^T == A-layout of x16)
                unsigned pk[2][2][2];
                #pragma unroll
                for (int n2 = 0; n2 < 2; ++n2) {
                    const int kcb = kt * BK + (h * 2 + n2) * 16 + qd * 4;
                    #pragma unroll
                    for (int mt = 0; mt < 2; ++mt) {
                        const int qrow = qrow_min + mt * 16 + li;
                        float p[4];
                        #pragma unroll
                        for (int r = 0; r < 4; ++r) {
                            float s = stt[n2][mt][r];
                            if (needmask && (kcb + r > qrow)) s = 0.f;
                            p[r] = s * s;
                        }
                        zpart[mt] += (p[0] + p[1]) + (p[2] + p[3]);
                        pk[n2][mt][0] = packbf(p[0], p[1]);
                        pk[n2][mt][1] = packbf(p[2], p[3]);
                    }
                }

                // O += P-half * V-half (x16 MFMA, B=V^T from swizzled LDS)
                #pragma unroll
                for (int s2 = 0; s2 < 2; ++s2) {
                    bf16x4 av[2];
                    #pragma unroll
                    for (int mt = 0; mt < 2; ++mt) {
                        union { unsigned u[2]; bf16x4 v; } cv;
                        cv.u[0] = pk[s2][mt][0]; cv.u[1] = pk[s2][mt][1];
                        av[mt] = cv.v;
                    }
                    const int sg = (h * 2 + s2) * 4 + qd;          // logical 8B group
                    #pragma unroll
                    for (int nd = 0; nd < 4; ++nd) {
                        const int d = nd * 16 + li;
                        bf16x4 vf = *(const bf16x4*)&Vst[cur][d][(sg ^ li) << 2];
                        #pragma unroll
                        for (int mt = 0; mt < 2; ++mt)
                            oacc[mt][nd] = __builtin_amdgcn_mfma_f32_16x16x16bf16_1k(
                                av[mt], vf, oacc[mt][nd], 0, 0, 0);
                    }
                }
            }
        }

        __syncthreads();   // drains vmcnt(0)+lgkmcnt(0): next tiles ready, cur reads done
    }

    // ---- epilogue: z reduce (quads) + divide + store ----
    float* odst = og + base + (size_t)qt * BQ * HD;
    #pragma unroll
    for (int mt = 0; mt < 2; ++mt) {
        float zf = zpart[mt];
        zf += __shfl_xor(zf, 16, 64);
        zf += __shfl_xor(zf, 32, 64);   // all lanes: z for qrow = mt*16 + li
        #pragma unroll
        for (int r = 0; r < 4; ++r) {
            float zr = __shfl(zf, qd * 4 + r, 64);
            float inv = 1.f / (zr + 1e-6f);
            int row = w * 32 + mt * 16 + qd * 4 + r;
            #pragma unroll
            for (int nd = 0; nd < 4; ++nd)
                odst[row * HD + nd * 16 + li] = oacc[mt][nd][r] * inv;
        }
    }
}

extern "C" void kernel_launch(void* const* d_in, const int* in_sizes, int n_in,
                              void* d_out, int out_size, void* d_ws, size_t ws_size,
                              hipStream_t stream) {
    const float* q = (const float*)d_in[0];
    const float* k = (const float*)d_in[1];
    const float* v = (const float*)d_in[2];
    float* out = (float*)d_out;

    unsigned short* kws = (unsigned short*)d_ws;
    unsigned short* vws = kws + (size_t)64 * SEQ * HD;   // +16MB; total ws use 32MB

    dim3 cgrid(64, 32);   // (head, k-tile)
    convert_kv_kernel<<<cgrid, dim3(256), 0, stream>>>(k, v, kws, vws);

    dim3 grid(64, 16);    // x=head (XCD affinity), y: heavy q-tiles first
    rebased_r8_kernel<<<grid, dim3(256), 0, stream>>>(q, kws, vws, out);
}

// Round 6
// 188.872 us; speedup vs baseline: 2.6658x; 1.0034x over previous
//
#include <hip/hip_runtime.h>
#include <hip/hip_bf16.h>

// ReBASED attention R9: counted-vmcnt pipeline + compile-time cur + z-via-MFMA.
// R8 post-mortem: bank conflicts 0, spill gone, FETCH compulsory — but each
// iteration's __syncthreads() drains vmcnt(0), serializing next-tile load
// latency into all 17 k-iters (2.6k cyc wall vs ~400 cyc work per block-iter).
// R9: (1) double-buffer pipeline with s_waitcnt vmcnt(4) + s_barrier (stage
// loads stay in flight across barriers; vmcnt(0) only at the final tile);
// (2) kt unrolled by 2 (iter count 2qt+2 even) so `cur` is compile-time and
// all swizzled LDS addresses are loop-invariant regs + immediate offsets;
// (3) z = row-sum of P computed by mfma(P, ones, zacc): moves 32 adds/iter
// from the busiest pipe (VALU 40%) to MFMA (28%), and zacc has the SAME
// C-layout as oacc -> epilogue shuffle-reduce deleted.
// Kept: bf16 pre-pass workspace in swizzled LDS-image layout, global_load_lds
// 16B staging, S^T orientation, Q-frags in regs, heavy-first grid(64,16),
// head-per-XCD affinity, (256,4).

#define SEQ 2048
#define HD  64
#define BQ  128
#define BK  64

typedef __attribute__((ext_vector_type(8))) short bf16x8;
typedef __attribute__((ext_vector_type(4))) short bf16x4;
typedef __attribute__((ext_vector_type(4))) float f32x4;
typedef __attribute__((ext_vector_type(4))) unsigned u32x4;

__device__ inline unsigned packbf(float a, float b) {
    __hip_bfloat162 h = __float22bfloat162_rn(make_float2(a, b));  // a->low, b->high
    union { __hip_bfloat162 h2; unsigned u; } cv; cv.h2 = h; return cv.u;
}

__device__ inline void gload_lds16(const void* g, void* l) {
    __builtin_amdgcn_global_load_lds(
        (const __attribute__((address_space(1))) unsigned*)g,
        (__attribute__((address_space(3))) unsigned*)l, 16, 0, 0);
}

// ---------------- pre-pass: K/V -> bf16 swizzled LDS-image tiles ----------------
// K tile (64x64): kws[tile][r][g'*8..] = K[r][g*8..+7], g' = g ^ (r&7)   (16B groups)
// V tile (64x64): vws[tile][d][sg'*4..] = V[sg*4..+3][d], sg' = sg ^ (d&15) (8B groups)
__global__ __launch_bounds__(256)
void convert_kv_kernel(const float* __restrict__ kg, const float* __restrict__ vg,
                       unsigned short* __restrict__ kws, unsigned short* __restrict__ vws) {
    const int head = blockIdx.x;
    const int kt   = blockIdx.y;
    const int t    = threadIdx.x;
    const size_t gbase = (size_t)head * SEQ * HD + (size_t)kt * BK * HD;
    unsigned short* ktile = kws + gbase;
    unsigned short* vtile = vws + gbase;

    {
        const int r = t >> 2, qr = t & 3;
        #pragma unroll
        for (int gg = 0; gg < 2; ++gg) {
            const int g = qr * 2 + gg;
            float4 a = *(const float4*)(kg + gbase + r * HD + g * 8);
            float4 b = *(const float4*)(kg + gbase + r * HD + g * 8 + 4);
            u32x4 pkd;
            pkd[0] = packbf(a.x, a.y); pkd[1] = packbf(a.z, a.w);
            pkd[2] = packbf(b.x, b.y); pkd[3] = packbf(b.z, b.w);
            *(u32x4*)(ktile + r * 64 + ((g ^ (r & 7)) << 3)) = pkd;
        }
    }
    {
        const int d = t & 63, sg0 = t >> 6;
        #pragma unroll
        for (int i = 0; i < 4; ++i) {
            const int sg = sg0 + i * 4;
            float v0 = vg[gbase + (sg * 4 + 0) * HD + d];
            float v1 = vg[gbase + (sg * 4 + 1) * HD + d];
            float v2 = vg[gbase + (sg * 4 + 2) * HD + d];
            float v3 = vg[gbase + (sg * 4 + 3) * HD + d];
            uint2 pkd = make_uint2(packbf(v0, v1), packbf(v2, v3));
            *(uint2*)(vtile + d * 64 + ((sg ^ (d & 15)) << 2)) = pkd;
        }
    }
}

// ---------------- main kernel ----------------
__global__ __launch_bounds__(256, 4)
void rebased_r9_kernel(const float* __restrict__ qg,
                       const unsigned short* __restrict__ kws,
                       const unsigned short* __restrict__ vws,
                       float* __restrict__ og) {
    __shared__ __align__(16) unsigned short Ks[2][BK][HD];    // swizzled image, 8KB each
    __shared__ __align__(16) unsigned short Vst[2][HD][BK];   // swizzled V^T image

    const int t    = threadIdx.x;
    const int lane = t & 63;
    const int w    = t >> 6;        // wave: q-rows [w*32, w*32+32)
    const int li   = lane & 15;
    const int qd   = lane >> 4;     // quad
    const int head = blockIdx.x;    // id%8 == head%8 -> head pinned to one XCD
    const int qt   = 15 - blockIdx.y;  // heavy-first (LPT)
    const int ktmax = 2 * qt + 1;      // odd -> iteration count even
    const size_t base = (size_t)head * SEQ * HD;

    // ---- Q fragments straight to registers (per-wave private; scaled) ----
    bf16x8 qf[2][2];   // [ks][mt]
    {
        const int qrow0 = qt * BQ + w * 32;
        #pragma unroll
        for (int mt = 0; mt < 2; ++mt) {
            const float* qrow = qg + base + (size_t)(qrow0 + mt * 16 + li) * HD;
            #pragma unroll
            for (int ks = 0; ks < 2; ++ks) {
                float4 a = *(const float4*)(qrow + ks * 32 + qd * 8);
                float4 b = *(const float4*)(qrow + ks * 32 + qd * 8 + 4);
                union { unsigned u[4]; bf16x8 v; } cv;
                cv.u[0] = packbf(a.x * 0.125f, a.y * 0.125f);
                cv.u[1] = packbf(a.z * 0.125f, a.w * 0.125f);
                cv.u[2] = packbf(b.x * 0.125f, b.y * 0.125f);
                cv.u[3] = packbf(b.z * 0.125f, b.w * 0.125f);
                qf[ks][mt] = cv.v;
            }
        }
    }

    // ---- DMA staging: wave w fills bytes [w*1024 + lane*16) of each 4KB half ----
    const int woff = w * 1024;
    const int goff = woff + lane * 16;
    #define STAGE(b, kt2)                                                          \
    {                                                                              \
        const char* ksrc = (const char*)(kws + base + (size_t)(kt2) * BK * HD);    \
        const char* vsrc = (const char*)(vws + base + (size_t)(kt2) * BK * HD);    \
        char* kdst = (char*)&Ks[b][0][0];                                          \
        char* vdst = (char*)&Vst[b][0][0];                                         \
        gload_lds16(ksrc + goff,        kdst + woff);                              \
        gload_lds16(ksrc + goff + 4096, kdst + woff + 4096);                       \
        gload_lds16(vsrc + goff,        vdst + woff);                              \
        gload_lds16(vsrc + goff + 4096, vdst + woff + 4096);                       \
    }

    // pipeline barriers: counted vmcnt, single-asm so nothing crosses
    #define WAITBAR4 asm volatile("s_waitcnt vmcnt(4)\n\ts_barrier" ::: "memory")
    #define WAITBAR0 asm volatile("s_waitcnt vmcnt(0)\n\ts_barrier" ::: "memory")
    #define ENDBAR   asm volatile("s_waitcnt lgkmcnt(0)\n\ts_barrier" ::: "memory")

    f32x4 oacc[2][4];
    f32x4 zacc[2];
    #pragma unroll
    for (int mt = 0; mt < 2; ++mt) {
        zacc[mt] = (f32x4){0.f, 0.f, 0.f, 0.f};
        #pragma unroll
        for (int nd = 0; nd < 4; ++nd) oacc[mt][nd] = (f32x4){0.f, 0.f, 0.f, 0.f};
    }
    bf16x4 onesb;
    { union { unsigned short us[4]; bf16x4 v; } o;
      o.us[0] = o.us[1] = o.us[2] = o.us[3] = 0x3F80; onesb = o.v; }

    const int qrow_min = qt * BQ + w * 32;

    #define COMPUTE(curq, ktq)                                                         \
    {                                                                                  \
        const bool active = ((ktq) * BK <= qrow_min + 31);                             \
        if (active) {                                                                  \
            const bool needmask = ((ktq) * BK + 63 > qrow_min);                        \
            _Pragma("unroll")                                                          \
            for (int h = 0; h < 2; ++h) {                                              \
                f32x4 stt[2][2];                                                       \
                _Pragma("unroll")                                                      \
                for (int n2 = 0; n2 < 2; ++n2)                                         \
                    _Pragma("unroll")                                                  \
                    for (int mt = 0; mt < 2; ++mt)                                     \
                        stt[n2][mt] = (f32x4){0.f, 0.f, 0.f, 0.f};                     \
                _Pragma("unroll")                                                      \
                for (int ks = 0; ks < 2; ++ks) {                                       \
                    bf16x8 kf[2];                                                      \
                    _Pragma("unroll")                                                  \
                    for (int n2 = 0; n2 < 2; ++n2) {                                   \
                        const int row = (h * 2 + n2) * 16 + li;                        \
                        const int grp = ((ks * 4 + qd) ^ (li & 7)) << 3;               \
                        kf[n2] = *(const bf16x8*)&Ks[curq][row][grp];                  \
                    }                                                                  \
                    _Pragma("unroll")                                                  \
                    for (int n2 = 0; n2 < 2; ++n2)                                     \
                        _Pragma("unroll")                                              \
                        for (int mt = 0; mt < 2; ++mt)                                 \
                            stt[n2][mt] = __builtin_amdgcn_mfma_f32_16x16x32_bf16(     \
                                kf[n2], qf[ks][mt], stt[n2][mt], 0, 0, 0);             \
                }                                                                      \
                unsigned pk[2][2][2];                                                  \
                _Pragma("unroll")                                                      \
                for (int n2 = 0; n2 < 2; ++n2) {                                       \
                    const int kcb = (ktq) * BK + (h * 2 + n2) * 16 + qd * 4;           \
                    _Pragma("unroll")                                                  \
                    for (int mt = 0; mt < 2; ++mt) {                                   \
                        const int qrow = qrow_min + mt * 16 + li;                      \
                        float p[4];                                                    \
                        _Pragma("unroll")                                              \
                        for (int r = 0; r < 4; ++r) {                                  \
                            float s = stt[n2][mt][r];                                  \
                            if (needmask && (kcb + r > qrow)) s = 0.f;                 \
                            p[r] = s * s;                                              \
                        }                                                              \
                        pk[n2][mt][0] = packbf(p[0], p[1]);                            \
                        pk[n2][mt][1] = packbf(p[2], p[3]);                            \
                    }                                                                  \
                }                                                                      \
                _Pragma("unroll")                                                      \
                for (int s2 = 0; s2 < 2; ++s2) {                                       \
                    bf16x4 av[2];                                                      \
                    _Pragma("unroll")                                                  \
                    for (int mt = 0; mt < 2; ++mt) {                                   \
                        union { unsigned u[2]; bf16x4 v; } cv;                         \
                        cv.u[0] = pk[s2][mt][0]; cv.u[1] = pk[s2][mt][1];              \
                        av[mt] = cv.v;                                                 \
                    }                                                                  \
                    _Pragma("unroll")                                                  \
                    for (int mt = 0; mt < 2; ++mt)                                     \
                        zacc[mt] = __builtin_amdgcn_mfma_f32_16x16x16bf16_1k(          \
                            av[mt], onesb, zacc[mt], 0, 0, 0);                         \
                    const int sg = (h * 2 + s2) * 4 + qd;                              \
                    _Pragma("unroll")                                                  \
                    for (int nd = 0; nd < 4; ++nd) {                                   \
                        const int d = nd * 16 + li;                                    \
                        bf16x4 vf = *(const bf16x4*)&Vst[curq][d][(sg ^ li) << 2];     \
                        _Pragma("unroll")                                              \
                        for (int mt = 0; mt < 2; ++mt)                                 \
                            oacc[mt][nd] = __builtin_amdgcn_mfma_f32_16x16x16bf16_1k(  \
                                av[mt], vf, oacc[mt][nd], 0, 0, 0);                    \
                    }                                                                  \
                }                                                                      \
            }                                                                          \
        }                                                                              \
    }

    STAGE(0, 0);   // 4 loads in flight

    for (int kt = 0; kt <= ktmax; kt += 2) {
        // ---- body A: cur=0, iter kt (kt even, ktmax odd -> kt < ktmax always) ----
        STAGE(1, kt + 1);     // outstanding: 8
        WAITBAR4;             // stage(kt) landed for this wave; barrier -> for all waves
        COMPUTE(0, kt);
        ENDBAR;               // all waves done reading buf0 before its next overwrite

        // ---- body B: cur=1, iter kt+1 ----
        if (kt + 1 < ktmax) { STAGE(0, kt + 2); WAITBAR4; }
        else                { WAITBAR0; }                    // final tile: full drain
        COMPUTE(1, kt + 1);
        if (kt + 1 < ktmax) { ENDBAR; }
    }

    // ---- epilogue: zacc has the same C-layout as oacc -> local divide, no shuffles ----
    float* odst = og + base + (size_t)qt * BQ * HD;
    #pragma unroll
    for (int mt = 0; mt < 2; ++mt) {
        #pragma unroll
        for (int r = 0; r < 4; ++r) {
            float inv = 1.f / (zacc[mt][r] + 1e-6f);
            int row = w * 32 + mt * 16 + qd * 4 + r;
            #pragma unroll
            for (int nd = 0; nd < 4; ++nd)
                odst[row * HD + nd * 16 + li] = oacc[mt][nd][r] * inv;
        }
    }
}

extern "C" void kernel_launch(void* const* d_in, const int* in_sizes, int n_in,
                              void* d_out, int out_size, void* d_ws, size_t ws_size,
                              hipStream_t stream) {
    const float* q = (const float*)d_in[0];
    const float* k = (const float*)d_in[1];
    const float* v = (const float*)d_in[2];
    float* out = (float*)d_out;

    unsigned short* kws = (unsigned short*)d_ws;
    unsigned short* vws = kws + (size_t)64 * SEQ * HD;   // +16MB; total ws use 32MB

    dim3 cgrid(64, 32);   // (head, k-tile)
    convert_kv_kernel<<<cgrid, dim3(256), 0, stream>>>(k, v, kws, vws);

    dim3 grid(64, 16);    // x=head (XCD affinity), y: heavy q-tiles first
    rebased_r9_kernel<<<grid, dim3(256), 0, stream>>>(q, kws, vws, out);
}

// Round 7
// 188.749 us; speedup vs baseline: 2.6675x; 1.0006x over previous
//
#include <hip/hip_runtime.h>
#include <hip/hip_bf16.h>

// ReBASED attention R10: CU-load-balanced qt permutation + s_setprio on MFMA.
// R9 post-mortem: all pipes <=36% busy; avg occupancy 33% with grid=1024 =
// exactly 4 blocks/CU resident at t=0 and no backfill. HW mapping (id%8=XCD,
// id/8%32=CU) co-locates blocks y,y+4,y+8,y+12 (same head). With qt=15-y a
// CU's iter total was 80-8*y0 (80 vs 56 imbalance -> idle drain tail).
// R10: qt = {y<8: 15-y; y<12: y-4; else y-12} -> every CU gets qt-sum 30 =
// exactly 68 iters (ideal makespan), same-head co-residency preserved (L2 hits
// on shared K/V tiles). Plus T5: s_setprio(1) around MFMA clusters -- our
// counted-vmcnt phase-split structure is the proven regime for it.
// Kept from R9: bf16 pre-pass workspace (swizzled LDS-image), global_load_lds
// 16B staging, counted vmcnt(4) pipeline (never 0 in steady state),
// compile-time cur via kt-by-2 unroll, z-via-MFMA (zacc C-layout == oacc),
// S^T orientation, Q-frags in regs, head-per-XCD grid, (256,4).

#define SEQ 2048
#define HD  64
#define BQ  128
#define BK  64

typedef __attribute__((ext_vector_type(8))) short bf16x8;
typedef __attribute__((ext_vector_type(4))) short bf16x4;
typedef __attribute__((ext_vector_type(4))) float f32x4;
typedef __attribute__((ext_vector_type(4))) unsigned u32x4;

__device__ inline unsigned packbf(float a, float b) {
    __hip_bfloat162 h = __float22bfloat162_rn(make_float2(a, b));  // a->low, b->high
    union { __hip_bfloat162 h2; unsigned u; } cv; cv.h2 = h; return cv.u;
}

__device__ inline void gload_lds16(const void* g, void* l) {
    __builtin_amdgcn_global_load_lds(
        (const __attribute__((address_space(1))) unsigned*)g,
        (__attribute__((address_space(3))) unsigned*)l, 16, 0, 0);
}

// ---------------- pre-pass: K/V -> bf16 swizzled LDS-image tiles ----------------
// K tile (64x64): kws[tile][r][g'*8..] = K[r][g*8..+7], g' = g ^ (r&7)   (16B groups)
// V tile (64x64): vws[tile][d][sg'*4..] = V[sg*4..+3][d], sg' = sg ^ (d&15) (8B groups)
__global__ __launch_bounds__(256)
void convert_kv_kernel(const float* __restrict__ kg, const float* __restrict__ vg,
                       unsigned short* __restrict__ kws, unsigned short* __restrict__ vws) {
    const int head = blockIdx.x;
    const int kt   = blockIdx.y;
    const int t    = threadIdx.x;
    const size_t gbase = (size_t)head * SEQ * HD + (size_t)kt * BK * HD;
    unsigned short* ktile = kws + gbase;
    unsigned short* vtile = vws + gbase;

    {
        const int r = t >> 2, qr = t & 3;
        #pragma unroll
        for (int gg = 0; gg < 2; ++gg) {
            const int g = qr * 2 + gg;
            float4 a = *(const float4*)(kg + gbase + r * HD + g * 8);
            float4 b = *(const float4*)(kg + gbase + r * HD + g * 8 + 4);
            u32x4 pkd;
            pkd[0] = packbf(a.x, a.y); pkd[1] = packbf(a.z, a.w);
            pkd[2] = packbf(b.x, b.y); pkd[3] = packbf(b.z, b.w);
            *(u32x4*)(ktile + r * 64 + ((g ^ (r & 7)) << 3)) = pkd;
        }
    }
    {
        const int d = t & 63, sg0 = t >> 6;
        #pragma unroll
        for (int i = 0; i < 4; ++i) {
            const int sg = sg0 + i * 4;
            float v0 = vg[gbase + (sg * 4 + 0) * HD + d];
            float v1 = vg[gbase + (sg * 4 + 1) * HD + d];
            float v2 = vg[gbase + (sg * 4 + 2) * HD + d];
            float v3 = vg[gbase + (sg * 4 + 3) * HD + d];
            uint2 pkd = make_uint2(packbf(v0, v1), packbf(v2, v3));
            *(uint2*)(vtile + d * 64 + ((sg ^ (d & 15)) << 2)) = pkd;
        }
    }
}

// ---------------- main kernel ----------------
__global__ __launch_bounds__(256, 4)
void rebased_r10_kernel(const float* __restrict__ qg,
                        const unsigned short* __restrict__ kws,
                        const unsigned short* __restrict__ vws,
                        float* __restrict__ og) {
    __shared__ __align__(16) unsigned short Ks[2][BK][HD];    // swizzled image, 8KB each
    __shared__ __align__(16) unsigned short Vst[2][HD][BK];   // swizzled V^T image

    const int t    = threadIdx.x;
    const int lane = t & 63;
    const int w    = t >> 6;        // wave: q-rows [w*32, w*32+32)
    const int li   = lane & 15;
    const int qd   = lane >> 4;     // quad
    const int head = blockIdx.x;    // id%8 == head%8 -> head pinned to one XCD
    const int y    = blockIdx.y;
    // Balanced permutation: co-resident blocks on a CU are y, y+4, y+8, y+12
    // (same head). qt-sums per CU = 30 -> exactly 68 k-iterations per CU.
    const int qt   = (y < 8) ? (15 - y) : ((y < 12) ? (y - 4) : (y - 12));
    const int ktmax = 2 * qt + 1;      // odd -> iteration count even
    const size_t base = (size_t)head * SEQ * HD;

    // ---- Q fragments straight to registers (per-wave private; scaled) ----
    bf16x8 qf[2][2];   // [ks][mt]
    {
        const int qrow0 = qt * BQ + w * 32;
        #pragma unroll
        for (int mt = 0; mt < 2; ++mt) {
            const float* qrow = qg + base + (size_t)(qrow0 + mt * 16 + li) * HD;
            #pragma unroll
            for (int ks = 0; ks < 2; ++ks) {
                float4 a = *(const float4*)(qrow + ks * 32 + qd * 8);
                float4 b = *(const float4*)(qrow + ks * 32 + qd * 8 + 4);
                union { unsigned u[4]; bf16x8 v; } cv;
                cv.u[0] = packbf(a.x * 0.125f, a.y * 0.125f);
                cv.u[1] = packbf(a.z * 0.125f, a.w * 0.125f);
                cv.u[2] = packbf(b.x * 0.125f, b.y * 0.125f);
                cv.u[3] = packbf(b.z * 0.125f, b.w * 0.125f);
                qf[ks][mt] = cv.v;
            }
        }
    }

    // ---- DMA staging: wave w fills bytes [w*1024 + lane*16) of each 4KB half ----
    const int woff = w * 1024;
    const int goff = woff + lane * 16;
    #define STAGE(b, kt2)                                                          \
    {                                                                              \
        const char* ksrc = (const char*)(kws + base + (size_t)(kt2) * BK * HD);    \
        const char* vsrc = (const char*)(vws + base + (size_t)(kt2) * BK * HD);    \
        char* kdst = (char*)&Ks[b][0][0];                                          \
        char* vdst = (char*)&Vst[b][0][0];                                         \
        gload_lds16(ksrc + goff,        kdst + woff);                              \
        gload_lds16(ksrc + goff + 4096, kdst + woff + 4096);                       \
        gload_lds16(vsrc + goff,        vdst + woff);                              \
        gload_lds16(vsrc + goff + 4096, vdst + woff + 4096);                       \
    }

    // pipeline barriers: counted vmcnt, single-asm so nothing crosses
    #define WAITBAR4 asm volatile("s_waitcnt vmcnt(4)\n\ts_barrier" ::: "memory")
    #define WAITBAR0 asm volatile("s_waitcnt vmcnt(0)\n\ts_barrier" ::: "memory")
    #define ENDBAR   asm volatile("s_waitcnt lgkmcnt(0)\n\ts_barrier" ::: "memory")

    f32x4 oacc[2][4];
    f32x4 zacc[2];
    #pragma unroll
    for (int mt = 0; mt < 2; ++mt) {
        zacc[mt] = (f32x4){0.f, 0.f, 0.f, 0.f};
        #pragma unroll
        for (int nd = 0; nd < 4; ++nd) oacc[mt][nd] = (f32x4){0.f, 0.f, 0.f, 0.f};
    }
    bf16x4 onesb;
    { union { unsigned short us[4]; bf16x4 v; } o;
      o.us[0] = o.us[1] = o.us[2] = o.us[3] = 0x3F80; onesb = o.v; }

    const int qrow_min = qt * BQ + w * 32;

    #define COMPUTE(curq, ktq)                                                         \
    {                                                                                  \
        const bool active = ((ktq) * BK <= qrow_min + 31);                             \
        if (active) {                                                                  \
            const bool needmask = ((ktq) * BK + 63 > qrow_min);                        \
            _Pragma("unroll")                                                          \
            for (int h = 0; h < 2; ++h) {                                              \
                f32x4 stt[2][2];                                                       \
                _Pragma("unroll")                                                      \
                for (int n2 = 0; n2 < 2; ++n2)                                         \
                    _Pragma("unroll")                                                  \
                    for (int mt = 0; mt < 2; ++mt)                                     \
                        stt[n2][mt] = (f32x4){0.f, 0.f, 0.f, 0.f};                     \
                _Pragma("unroll")                                                      \
                for (int ks = 0; ks < 2; ++ks) {                                       \
                    bf16x8 kf[2];                                                      \
                    _Pragma("unroll")                                                  \
                    for (int n2 = 0; n2 < 2; ++n2) {                                   \
                        const int row = (h * 2 + n2) * 16 + li;                        \
                        const int grp = ((ks * 4 + qd) ^ (li & 7)) << 3;               \
                        kf[n2] = *(const bf16x8*)&Ks[curq][row][grp];                  \
                    }                                                                  \
                    __builtin_amdgcn_s_setprio(1);                                     \
                    _Pragma("unroll")                                                  \
                    for (int n2 = 0; n2 < 2; ++n2)                                     \
                        _Pragma("unroll")                                              \
                        for (int mt = 0; mt < 2; ++mt)                                 \
                            stt[n2][mt] = __builtin_amdgcn_mfma_f32_16x16x32_bf16(     \
                                kf[n2], qf[ks][mt], stt[n2][mt], 0, 0, 0);             \
                    __builtin_amdgcn_s_setprio(0);                                     \
                }                                                                      \
                unsigned pk[2][2][2];                                                  \
                _Pragma("unroll")                                                      \
                for (int n2 = 0; n2 < 2; ++n2) {                                       \
                    const int kcb = (ktq) * BK + (h * 2 + n2) * 16 + qd * 4;           \
                    _Pragma("unroll")                                                  \
                    for (int mt = 0; mt < 2; ++mt) {                                   \
                        const int qrow = qrow_min + mt * 16 + li;                      \
                        float p[4];                                                    \
                        _Pragma("unroll")                                              \
                        for (int r = 0; r < 4; ++r) {                                  \
                            float s = stt[n2][mt][r];                                  \
                            if (needmask && (kcb + r > qrow)) s = 0.f;                 \
                            p[r] = s * s;                                              \
                        }                                                              \
                        pk[n2][mt][0] = packbf(p[0], p[1]);                            \
                        pk[n2][mt][1] = packbf(p[2], p[3]);                            \
                    }                                                                  \
                }                                                                      \
                _Pragma("unroll")                                                      \
                for (int s2 = 0; s2 < 2; ++s2) {                                       \
                    bf16x4 av[2];                                                      \
                    _Pragma("unroll")                                                  \
                    for (int mt = 0; mt < 2; ++mt) {                                   \
                        union { unsigned u[2]; bf16x4 v; } cv;                         \
                        cv.u[0] = pk[s2][mt][0]; cv.u[1] = pk[s2][mt][1];              \
                        av[mt] = cv.v;                                                 \
                    }                                                                  \
                    const int sg = (h * 2 + s2) * 4 + qd;                              \
                    __builtin_amdgcn_s_setprio(1);                                     \
                    _Pragma("unroll")                                                  \
                    for (int mt = 0; mt < 2; ++mt)                                     \
                        zacc[mt] = __builtin_amdgcn_mfma_f32_16x16x16bf16_1k(          \
                            av[mt], onesb, zacc[mt], 0, 0, 0);                         \
                    _Pragma("unroll")                                                  \
                    for (int nd = 0; nd < 4; ++nd) {                                   \
                        const int d = nd * 16 + li;                                    \
                        bf16x4 vf = *(const bf16x4*)&Vst[curq][d][(sg ^ li) << 2];     \
                        _Pragma("unroll")                                              \
                        for (int mt = 0; mt < 2; ++mt)                                 \
                            oacc[mt][nd] = __builtin_amdgcn_mfma_f32_16x16x16bf16_1k(  \
                                av[mt], vf, oacc[mt][nd], 0, 0, 0);                    \
                    }                                                                  \
                    __builtin_amdgcn_s_setprio(0);                                     \
                }                                                                      \
            }                                                                          \
        }                                                                              \
    }

    STAGE(0, 0);   // 4 loads in flight

    for (int kt = 0; kt <= ktmax; kt += 2) {
        // ---- body A: cur=0, iter kt (kt even, ktmax odd -> kt < ktmax always) ----
        STAGE(1, kt + 1);     // outstanding: 8
        WAITBAR4;             // stage(kt) landed for this wave; barrier -> for all waves
        COMPUTE(0, kt);
        ENDBAR;               // all waves done reading buf0 before its next overwrite

        // ---- body B: cur=1, iter kt+1 ----
        if (kt + 1 < ktmax) { STAGE(0, kt + 2); WAITBAR4; }
        else                { WAITBAR0; }                    // final tile: full drain
        COMPUTE(1, kt + 1);
        if (kt + 1 < ktmax) { ENDBAR; }
    }

    // ---- epilogue: zacc has the same C-layout as oacc -> local divide, no shuffles ----
    float* odst = og + base + (size_t)qt * BQ * HD;
    #pragma unroll
    for (int mt = 0; mt < 2; ++mt) {
        #pragma unroll
        for (int r = 0; r < 4; ++r) {
            float inv = 1.f / (zacc[mt][r] + 1e-6f);
            int row = w * 32 + mt * 16 + qd * 4 + r;
            #pragma unroll
            for (int nd = 0; nd < 4; ++nd)
                odst[row * HD + nd * 16 + li] = oacc[mt][nd][r] * inv;
        }
    }
}

extern "C" void kernel_launch(void* const* d_in, const int* in_sizes, int n_in,
                              void* d_out, int out_size, void* d_ws, size_t ws_size,
                              hipStream_t stream) {
    const float* q = (const float*)d_in[0];
    const float* k = (const float*)d_in[1];
    const float* v = (const float*)d_in[2];
    float* out = (float*)d_out;

    unsigned short* kws = (unsigned short*)d_ws;
    unsigned short* vws = kws + (size_t)64 * SEQ * HD;   // +16MB; total ws use 32MB

    dim3 cgrid(64, 32);   // (head, k-tile)
    convert_kv_kernel<<<cgrid, dim3(256), 0, stream>>>(k, v, kws, vws);

    dim3 grid(64, 16);    // x=head (XCD affinity), y -> balanced qt permutation
    rebased_r10_kernel<<<grid, dim3(256), 0, stream>>>(q, kws, vws, out);
}